// Round 10
// baseline (724.749 us; speedup 1.0000x reference)
//
#include <hip/hip_runtime.h>
#include <hip/hip_bf16.h>
#include <hip/hip_cooperative_groups.h>

namespace cg = cooperative_groups;

// DRew-GIN: N=50000, E=800000, D=128, L=3, NU=1.
// R12 (324us, proven): standalone source-major gathers + b_lds lgemm.
// R13/R15 fusion: REJECTED — counters showed latency-bound (nothing
//   saturated); fusion cut gather concurrency 12x. Reverted.
// R17: R12 structure, but (a) whole CSR build + init in ONE cooperative
//   kernel (4 grid syncs, grid=1024 co-resident); (b) km1-major bucket ids
//   (proven R13/R15) -> identity worklist, sort machinery deleted.
//   7 launches: build | gatherA | lgemm0 | gatherB | lgemm1 | gatherC | lgemm2.
// R18/R19/R20: resubmit unchanged — R17 bench infra-failed (GPU timeouts).

#define NODES 50000
#define EDGES 800000
#define DIM   128
#define ND    ((long)NODES * DIM)
#define NB3   (3 * NODES)            // buckets: km1*NODES + d
#define NPART 4
#define PSIZE (NODES / NPART)        // 12500
#define NROWP 50048                  // row-padded tensors (tail tile slack)
#define NBLKS ((NB3 + 255) / 256)    // 587
#define EGRID ((EDGES + 255) / 256)  // 3125

typedef __attribute__((ext_vector_type(8))) short  bf16x8;
typedef __attribute__((ext_vector_type(4))) float  f32x4;

#define LDS_STRIDE 136   // bf16 elements; 272B rows

// ---------------------------------------------------------------------------
// Cooperative build kernel: P0 conv+zero | P1 hist | P2 scan_a | P3 scanc
// | P4 fill. grid=1024 blocks x 256 thr, guaranteed co-resident via
// __launch_bounds__(256,4) (4 blocks/CU x 256 CU).
__global__ __launch_bounds__(256, 4) void build_kernel(
    const float* __restrict__ x, const float* __restrict__ Ws,
    const float* __restrict__ Wk, __hip_bfloat16* __restrict__ xb0,
    __hip_bfloat16* __restrict__ xb1, __hip_bfloat16* __restrict__ xb2,
    __hip_bfloat16* __restrict__ WT, int* __restrict__ cursor,
    const int* __restrict__ ei, const int* __restrict__ attr,
    int* __restrict__ rowptr, int* __restrict__ blocksums,
    int* __restrict__ csr) {
  cg::grid_group grid = cg::this_grid();
  __shared__ int tmp[256];
  __shared__ int red[256];

  const int tid = threadIdx.x;
  const int gtid = blockIdx.x * 256 + tid;
  const int nth = gridDim.x * 256;            // 262144

  // ---- P0: x->bf16, weight transpose+convert, cursor zero, dummy rows ----
  for (int i = gtid; i < (int)(ND / 4); i += nth) {
    float4 v = ((const float4*)x)[i];
    union { __hip_bfloat16 h[4]; uint2 u; } pk;
    pk.h[0] = __float2bfloat16(v.x); pk.h[1] = __float2bfloat16(v.y);
    pk.h[2] = __float2bfloat16(v.z); pk.h[3] = __float2bfloat16(v.w);
    ((uint2*)xb0)[i] = pk.u;
  }
  for (int idx = gtid; idx < 12 * 16384; idx += nth) {
    int wb = idx >> 14, r = idx & 16383;
    int k = r >> 7, n = r & 127;
    const float* src = (wb < 3) ? (Ws + (long)wb * 16384) : (Wk + (long)(wb - 3) * 16384);
    WT[(long)wb * 16384 + n * 128 + k] = __float2bfloat16(src[r]);
  }
  for (int g = gtid; g < NB3; g += nth) cursor[g] = 0;
  if (gtid < 3 * DIM) {
    int which = gtid >> 7, dcol = gtid & 127;
    __hip_bfloat16* xb = (which == 0) ? xb0 : ((which == 1) ? xb1 : xb2);
    xb[(long)NODES * DIM + dcol] = __float2bfloat16(0.f);
  }
  grid.sync();

  // ---- P1: histogram (km1-major buckets) ----
  for (int e = gtid; e < EDGES; e += nth)
    atomicAdd(&cursor[(attr[e] - 1) * NODES + ei[EDGES + e]], 1);
  grid.sync();

  // ---- P2: per-block scan of padded counts ----
  if (blockIdx.x < NBLKS) {
    int gid = blockIdx.x * 256 + tid;
    int v = (gid < NB3) ? ((cursor[gid] + 3) & ~3) : 0;
    tmp[tid] = v;
    __syncthreads();
    for (int off = 1; off < 256; off <<= 1) {
      int t = (tid >= off) ? tmp[tid - off] : 0;
      __syncthreads();
      tmp[tid] += t;
      __syncthreads();
    }
    if (gid < NB3) rowptr[gid] = tmp[tid] - v;   // block-local exclusive
    if (tid == 255) blocksums[blockIdx.x] = tmp[255];
  }
  grid.sync();

  // ---- P3: add blocksum prefix (self-computed), pad-slack fill ----
  if (blockIdx.x < NBLKS) {
    int partial = 0;
    for (int i = tid; i < (int)blockIdx.x; i += 256) partial += blocksums[i];
    red[tid] = partial;
    __syncthreads();
    for (int off = 128; off > 0; off >>= 1) {
      if (tid < off) red[tid] += red[tid + off];
      __syncthreads();
    }
    int bsoff = red[0];
    int gid = blockIdx.x * 256 + tid;
    if (gid < NB3) {
      int cnt = cursor[gid];
      int pcnt = (cnt + 3) & ~3;
      int val = rowptr[gid] + bsoff;
      rowptr[gid] = val;
      cursor[gid] = val;
      for (int i = cnt; i < pcnt; ++i) csr[val + i] = NODES;
      if (gid == NB3 - 1) rowptr[NB3] = val + pcnt;
    }
  }
  grid.sync();

  // ---- P4: fill (NPART dst-range partition passes, virtual blocks) ----
  for (int vb = blockIdx.x; vb < EGRID * NPART; vb += gridDim.x) {
    int p = vb & (NPART - 1);
    int chunk = vb >> 2;
    int e = chunk * 256 + tid;
    if (e < EDGES) {
      int d = ei[EDGES + e];
      int lo = p * PSIZE;
      if (d >= lo && d < lo + PSIZE) {
        int pos = atomicAdd(&cursor[(attr[e] - 1) * NODES + d], 1);
        csr[pos] = ei[e];
      }
    }
  }
}

// ---------------------------------------------------------------------------
// Gather (R12 body, identity worklist): group id IS the km1-major bucket id.
// nwork = N / 2N / 3N selects km1 prefixes. 16-lane group per bucket.
__global__ __launch_bounds__(256, 6) void gather_kernel(
    const __hip_bfloat16* __restrict__ src,
    const int* __restrict__ rowptr, const int* __restrict__ csr,
    __hip_bfloat16* __restrict__ ag0, __hip_bfloat16* __restrict__ ag1,
    __hip_bfloat16* __restrict__ ag2, int nwork) {
  int group = (blockIdx.x * 256 + threadIdx.x) >> 4;
  int lane16 = threadIdx.x & 15;
  if (group >= nwork) return;
  int km1 = (group >= 2 * NODES) ? 2 : ((group >= NODES) ? 1 : 0);
  int d = group - km1 * NODES;
  __hip_bfloat16* ag = (km1 == 0) ? ag0 : ((km1 == 1) ? ag1 : ag2);
  int beg = rowptr[group], end = rowptr[group + 1];   // (end-beg)%4 == 0
  float a0 = 0.f, a1 = 0.f, a2 = 0.f, a3 = 0.f,
        a4 = 0.f, a5 = 0.f, a6 = 0.f, a7 = 0.f;
  for (int base = beg; base < end; base += 16) {
    int idxv = csr[base + lane16];            // slack-allocated
    int cnt = end - base; if (cnt > 16) cnt = 16;
    int q0 = __shfl(idxv, 0, 16);
    int q1 = __shfl(idxv, 1, 16);
    int q2 = __shfl(idxv, 2, 16);
    int q3 = __shfl(idxv, 3, 16);
    uint4 v0 = *(const uint4*)(src + (long)q0 * DIM + lane16 * 8);
    uint4 v1 = *(const uint4*)(src + (long)q1 * DIM + lane16 * 8);
    uint4 v2 = *(const uint4*)(src + (long)q2 * DIM + lane16 * 8);
    uint4 v3 = *(const uint4*)(src + (long)q3 * DIM + lane16 * 8);
    for (int j = 0; j < cnt; j += 4) {
      uint4 c0 = v0, c1 = v1, c2 = v2, c3 = v3;
      if (j + 4 < cnt) {                      // pipeline next 4 rows
        q0 = __shfl(idxv, j + 4, 16);
        q1 = __shfl(idxv, j + 5, 16);
        q2 = __shfl(idxv, j + 6, 16);
        q3 = __shfl(idxv, j + 7, 16);
        v0 = *(const uint4*)(src + (long)q0 * DIM + lane16 * 8);
        v1 = *(const uint4*)(src + (long)q1 * DIM + lane16 * 8);
        v2 = *(const uint4*)(src + (long)q2 * DIM + lane16 * 8);
        v3 = *(const uint4*)(src + (long)q3 * DIM + lane16 * 8);
      }
      a0 += __uint_as_float(c0.x << 16) + __uint_as_float(c1.x << 16)
          + __uint_as_float(c2.x << 16) + __uint_as_float(c3.x << 16);
      a1 += __uint_as_float(c0.x & 0xffff0000u) + __uint_as_float(c1.x & 0xffff0000u)
          + __uint_as_float(c2.x & 0xffff0000u) + __uint_as_float(c3.x & 0xffff0000u);
      a2 += __uint_as_float(c0.y << 16) + __uint_as_float(c1.y << 16)
          + __uint_as_float(c2.y << 16) + __uint_as_float(c3.y << 16);
      a3 += __uint_as_float(c0.y & 0xffff0000u) + __uint_as_float(c1.y & 0xffff0000u)
          + __uint_as_float(c2.y & 0xffff0000u) + __uint_as_float(c3.y & 0xffff0000u);
      a4 += __uint_as_float(c0.z << 16) + __uint_as_float(c1.z << 16)
          + __uint_as_float(c2.z << 16) + __uint_as_float(c3.z << 16);
      a5 += __uint_as_float(c0.z & 0xffff0000u) + __uint_as_float(c1.z & 0xffff0000u)
          + __uint_as_float(c2.z & 0xffff0000u) + __uint_as_float(c3.z & 0xffff0000u);
      a6 += __uint_as_float(c0.w << 16) + __uint_as_float(c1.w << 16)
          + __uint_as_float(c2.w << 16) + __uint_as_float(c3.w << 16);
      a7 += __uint_as_float(c0.w & 0xffff0000u) + __uint_as_float(c1.w & 0xffff0000u)
          + __uint_as_float(c2.w & 0xffff0000u) + __uint_as_float(c3.w & 0xffff0000u);
    }
  }
  union { __hip_bfloat16 h[8]; uint4 u; } pk;
  pk.h[0] = __float2bfloat16(a0); pk.h[1] = __float2bfloat16(a1);
  pk.h[2] = __float2bfloat16(a2); pk.h[3] = __float2bfloat16(a3);
  pk.h[4] = __float2bfloat16(a4); pk.h[5] = __float2bfloat16(a5);
  pk.h[6] = __float2bfloat16(a6); pk.h[7] = __float2bfloat16(a7);
  *(uint4*)(ag + (long)d * DIM + lane16 * 8) = pk.u;
}

// ---------------------------------------------------------------------------
// Layer GEMM (R12 version, proven): bf16 node state, A-frags direct from
// global, B staged in LDS.
__global__ __launch_bounds__(256, 4) void lgemm_kernel(
    const __hip_bfloat16* __restrict__ xbSelf,
    const __hip_bfloat16* __restrict__ ag0,
    const __hip_bfloat16* __restrict__ ag1,
    const __hip_bfloat16* __restrict__ ag2,
    const __hip_bfloat16* __restrict__ WT,
    const float* __restrict__ bs_t,
    const float* __restrict__ bk_t,
    const float* __restrict__ epsp,
    __hip_bfloat16* __restrict__ xnb,   // bf16 out (layers 0/1)
    float* __restrict__ xn,             // f32 out (final layer) or null
    int t) {
  __shared__ __hip_bfloat16 b_lds[128 * LDS_STRIDE];  // 34816 B

  int tid = threadIdx.x;
  long row0 = (long)blockIdx.x * 64;
  int wave = tid >> 6, lane = tid & 63;
  int l15 = lane & 15, q = lane >> 4;
  long arow = row0 + wave * 16 + l15;

  const __hip_bfloat16* Asrc[4] = {xbSelf, ag0, ag1, ag2};
  f32x4 out[8];

  for (int p = 0; p <= t + 1; ++p) {
    if (p > 0) __syncthreads();
    const __hip_bfloat16* Am = Asrc[p];
    uint4 af[4];
#pragma unroll
    for (int k0i = 0; k0i < 4; ++k0i)
      af[k0i] = *(const uint4*)(Am + arow * DIM + k0i * 32 + 8 * q);
    const __hip_bfloat16* W = (p == 0) ? (WT + (long)t * 16384)
                                       : (WT + (long)(3 + t * 3 + (p - 1)) * 16384);
    {
      const uint4* bq = (const uint4*)W;
#pragma unroll
      for (int i = 0; i < 8; ++i) {
        int idx = tid + 256 * i;
        int n = idx >> 4, k8 = idx & 15;
        uint4 v = bq[idx];
        *(uint4*)(b_lds + n * LDS_STRIDE + k8 * 8) = v;
      }
    }
    __syncthreads();

    f32x4 acc[8] = {};
#pragma unroll
    for (int k0i = 0; k0i < 4; ++k0i) {
      bf16x8 a = __builtin_bit_cast(bf16x8, af[k0i]);
#pragma unroll
      for (int j = 0; j < 8; ++j) {
        bf16x8 bfr = *(const bf16x8*)(b_lds + (16 * j + l15) * LDS_STRIDE + k0i * 32 + 8 * q);
        acc[j] = __builtin_amdgcn_mfma_f32_16x16x32_bf16(a, bfr, acc[j], 0, 0, 0);
      }
    }
    if (p == 0) {
      float sc = 1.0f + *epsp;
#pragma unroll
      for (int j = 0; j < 8; ++j) {
        float b = bs_t[16 * j + l15];
#pragma unroll
        for (int r = 0; r < 4; ++r) out[j][r] = sc * fmaxf(acc[j][r] + b, 0.f);
      }
    } else {
      const float* bb = bk_t + (p - 1) * 128;
#pragma unroll
      for (int j = 0; j < 8; ++j) {
        float b = bb[16 * j + l15];
#pragma unroll
        for (int r = 0; r < 4; ++r) out[j][r] += fmaxf(acc[j][r] + b, 0.f);
      }
    }
  }

  long rbase = row0 + wave * 16 + q * 4;
  bool fin = (xn != nullptr);
#pragma unroll
  for (int j = 0; j < 8; ++j) {
    int col = 16 * j + l15;
#pragma unroll
    for (int r = 0; r < 4; ++r) {
      long grow = rbase + r;
      if (grow < NODES) {
        float res = __bfloat162float(xbSelf[grow * DIM + col]);
        float v = res + fmaxf(out[j][r], 0.f);
        if (fin) xn[grow * DIM + col] = v;
        else     xnb[grow * DIM + col] = __float2bfloat16(v);
      }
    }
  }
}

// ---------------------------------------------------------------------------
extern "C" void kernel_launch(void* const* d_in, const int* in_sizes, int n_in,
                              void* d_out, int out_size, void* d_ws, size_t ws_size,
                              hipStream_t stream) {
  const float* x    = (const float*)d_in[0];
  const int*   ei   = (const int*)d_in[1];
  const int*   attr = (const int*)d_in[2];
  const float* Ws   = (const float*)d_in[3];
  const float* bs   = (const float*)d_in[4];
  const float* Wk   = (const float*)d_in[5];
  const float* bk   = (const float*)d_in[6];
  const float* eps  = (const float*)d_in[7];
  float* out = (float*)d_out;

  char* ws = (char*)d_ws;
  size_t off = 0;
  auto alloc = [&](size_t bytes) { char* p = ws + off; off += (bytes + 255) & ~(size_t)255; return p; };
  const size_t ROWB = (size_t)NROWP * DIM * 2;
  __hip_bfloat16* xb0  = (__hip_bfloat16*)alloc(ROWB);
  __hip_bfloat16* xb1  = (__hip_bfloat16*)alloc(ROWB);
  __hip_bfloat16* xb2  = (__hip_bfloat16*)alloc(ROWB);
  __hip_bfloat16* agA0 = (__hip_bfloat16*)alloc(ROWB);  // src xb0: layer0 k=1
  __hip_bfloat16* agA1 = (__hip_bfloat16*)alloc(ROWB);  // src xb0: layer1 k=2
  __hip_bfloat16* agA2 = (__hip_bfloat16*)alloc(ROWB);  // src xb0: layer2 k=3
  __hip_bfloat16* agB0 = (__hip_bfloat16*)alloc(ROWB);  // src xb1: layer1 k=1
  __hip_bfloat16* agB1 = (__hip_bfloat16*)alloc(ROWB);  // src xb1: layer2 k=2
  __hip_bfloat16* agC0 = (__hip_bfloat16*)alloc(ROWB);  // src xb2: layer2 k=1
  __hip_bfloat16* WT   = (__hip_bfloat16*)alloc(12 * 16384 * 2);
  int* cursor    = (int*)alloc((size_t)NB3 * 4);
  int* rowptr    = (int*)alloc((size_t)(NB3 + 1) * 4 + 256);
  int* blocksums = (int*)alloc(1024 * 4);
  int* csr_src   = (int*)alloc((size_t)(EDGES + 4 * NB3 + 64) * 4);

  // --- 1: cooperative build (init + hist + scan + fill) ---
  {
    void* args[] = {(void*)&x, (void*)&Ws, (void*)&Wk, (void*)&xb0, (void*)&xb1,
                    (void*)&xb2, (void*)&WT, (void*)&cursor, (void*)&ei,
                    (void*)&attr, (void*)&rowptr, (void*)&blocksums,
                    (void*)&csr_src};
    hipLaunchCooperativeKernel((const void*)build_kernel, dim3(1024), dim3(256),
                               args, 0, stream);
  }

  auto glaunch = [&](int nwork, const __hip_bfloat16* src, __hip_bfloat16* a0,
                     __hip_bfloat16* a1, __hip_bfloat16* a2) {
    int blocks = (nwork * 16 + 255) / 256;
    hipLaunchKernelGGL(gather_kernel, dim3(blocks), dim3(256), 0, stream,
                       src, rowptr, csr_src, a0, a1, a2, nwork);
  };
  int ggrid = (NODES + 63) / 64;   // 782

  // --- 2: Gather A: all km1 from xb0 ---
  glaunch(3 * NODES, xb0, agA0, agA1, agA2);
  // --- 3: Layer 0 ---
  hipLaunchKernelGGL(lgemm_kernel, dim3(ggrid), dim3(256), 0, stream,
                     xb0, agA0, agA0, agA0, WT, bs + 0, bk + 0, eps + 0,
                     xb1, (float*)nullptr, 0);
  // --- 4: Gather B: km1 in {0,1} from xb1 ---
  glaunch(2 * NODES, xb1, agB0, agB1, agB1);
  // --- 5: Layer 1: k=1 -> agB0 (xb1), k=2 -> agA1 (xb0) ---
  hipLaunchKernelGGL(lgemm_kernel, dim3(ggrid), dim3(256), 0, stream,
                     xb1, agB0, agA1, agA1, WT, bs + 128, bk + 3 * 128, eps + 1,
                     xb2, (float*)nullptr, 1);
  // --- 6: Gather C: km1=0 from xb2 ---
  glaunch(NODES, xb2, agC0, agC0, agC0);
  // --- 7: Layer 2: k=1 -> agC0 (xb2), k=2 -> agB1 (xb1), k=3 -> agA2 (xb0) ---
  hipLaunchKernelGGL(lgemm_kernel, dim3(ggrid), dim3(256), 0, stream,
                     xb2, agC0, agB1, agA2, WT, bs + 256, bk + 6 * 128, eps + 2,
                     (__hip_bfloat16*)nullptr, out, 2);
}

// Round 14
// 315.774 us; speedup vs baseline: 2.2952x; 2.2952x over previous
//
#include <hip/hip_runtime.h>
#include <hip/hip_bf16.h>

// DRew-GIN: N=50000, E=800000, D=128, L=3, NU=1.
// R12 (324us, proven): standalone source-major gathers + b_lds lgemm, sorted wl.
// R13/R15 fusion: REJECTED (latency-bound; concurrency loss).
// R17 cooperative build: REJECTED — build_kernel 490us, VALU 0.6%, HBM 3.4%:
//   grid.sync() costs ~120us each on this runtime (4 syncs ~= 480us).
//   BUT R17 passed -> km1-major CSR + identity worklist proven correct.
// R21: discrete front-end (R12's proven kernels, km1-major) + identity
//   worklist (no sort machinery). 11 launches:
//   init|hist|scan_a|scanc|fill|gatherA|lgemm0|gatherB|lgemm1|gatherC|lgemm2.
// R22/R23/R24: resubmit unchanged — R21 bench infra-failed (GPU timeouts).

#define NODES 50000
#define EDGES 800000
#define DIM   128
#define ND    ((long)NODES * DIM)
#define NB3   (3 * NODES)            // buckets: km1*NODES + d
#define NPART 4
#define PSIZE (NODES / NPART)        // 12500
#define NROWP 50048                  // row-padded tensors (tail tile slack)
#define NBLKS ((NB3 + 255) / 256)    // 587

typedef __attribute__((ext_vector_type(8))) short  bf16x8;
typedef __attribute__((ext_vector_type(4))) float  f32x4;

#define LDS_STRIDE 136   // bf16 elements; 272B rows

// ---------------------------------------------------------------------------
// init: x->bf16 shadow, weight conversion, dummy-row zero, cursor zero.
__global__ __launch_bounds__(256) void init_kernel(
    const float* __restrict__ x, const float* __restrict__ Ws,
    const float* __restrict__ Wk, __hip_bfloat16* __restrict__ xb0,
    __hip_bfloat16* __restrict__ xb1, __hip_bfloat16* __restrict__ xb2,
    __hip_bfloat16* __restrict__ WT, int* __restrict__ cursor) {
  int b = blockIdx.x, tid = threadIdx.x;
  long i = (long)b * 256 + tid;
  if (i < ND / 4) {
    float4 v = ((const float4*)x)[i];
    union { __hip_bfloat16 h[4]; uint2 u; } pk;
    pk.h[0] = __float2bfloat16(v.x); pk.h[1] = __float2bfloat16(v.y);
    pk.h[2] = __float2bfloat16(v.z); pk.h[3] = __float2bfloat16(v.w);
    ((uint2*)xb0)[i] = pk.u;
  }
  if (b < 12) {
    const float* src = (b < 3) ? (Ws + (long)b * 16384) : (Wk + (long)(b - 3) * 16384);
    __hip_bfloat16* dst = WT + (long)b * 16384;
    for (int idx = tid; idx < 16384; idx += 256) {
      int k = idx >> 7, n = idx & 127;
      dst[n * 128 + k] = __float2bfloat16(src[idx]);
    }
  }
  if (b >= 12 && b < 12 + NBLKS) {
    int g = (b - 12) * 256 + tid;
    if (g < NB3) cursor[g] = 0;
  }
  if (b == 599 && tid < DIM) {
    xb0[(long)NODES * DIM + tid] = __float2bfloat16(0.f);
    xb1[(long)NODES * DIM + tid] = __float2bfloat16(0.f);
    xb2[(long)NODES * DIM + tid] = __float2bfloat16(0.f);
  }
}

// ---------------------------------------------------------------------------
// CSR build (pad-to-4), km1-major bucket ids: bid = (attr-1)*NODES + dst.
__global__ __launch_bounds__(256) void hist_kernel(
    const int* __restrict__ ei, const int* __restrict__ attr,
    int* __restrict__ counts, int E) {
  int e = blockIdx.x * 256 + threadIdx.x;
  if (e >= E) return;
  atomicAdd(&counts[(attr[e] - 1) * NODES + ei[E + e]], 1);
}

__global__ __launch_bounds__(256) void scan_a_kernel(
    const int* __restrict__ counts, int* __restrict__ partial,
    int* __restrict__ blocksums, int n) {
  __shared__ int tmp[256];
  int gid = blockIdx.x * 256 + threadIdx.x;
  int v = (gid < n) ? ((counts[gid] + 3) & ~3) : 0;
  tmp[threadIdx.x] = v;
  __syncthreads();
  for (int off = 1; off < 256; off <<= 1) {
    int t = (threadIdx.x >= off) ? tmp[threadIdx.x - off] : 0;
    __syncthreads();
    tmp[threadIdx.x] += t;
    __syncthreads();
  }
  if (gid < n) partial[gid] = tmp[threadIdx.x] - v;
  if (threadIdx.x == 255) blocksums[blockIdx.x] = tmp[255];
}

// scan_c: computes its own exclusive blocksum prefix, writes rowptr/cursor,
// fills pad-slack csr entries with dummy node id. (Proven R13/R17.)
__global__ __launch_bounds__(256) void scanc_kernel(
    int* __restrict__ rowptr, int* __restrict__ cursor,
    const int* __restrict__ blocksums, int* __restrict__ csr, int n) {
  __shared__ int red[256];
  int tid = threadIdx.x;
  int partial = 0;
  for (int i = tid; i < blockIdx.x; i += 256) partial += blocksums[i];
  red[tid] = partial;
  __syncthreads();
  for (int off = 128; off > 0; off >>= 1) {
    if (tid < off) red[tid] += red[tid + off];
    __syncthreads();
  }
  int bsoff = red[0];
  int gid = blockIdx.x * 256 + tid;
  if (gid < n) {
    int cnt = cursor[gid];
    int pcnt = (cnt + 3) & ~3;
    int val = rowptr[gid] + bsoff;
    rowptr[gid] = val;
    cursor[gid] = val;
    for (int i = cnt; i < pcnt; ++i) csr[val + i] = NODES;
    if (gid == n - 1) rowptr[n] = val + pcnt;
  }
}

__global__ __launch_bounds__(256) void fill_kernel(
    const int* __restrict__ ei, const int* __restrict__ attr,
    int* __restrict__ cursor, int* __restrict__ csr_src, int E) {
  int p = blockIdx.x & (NPART - 1);
  int chunk = blockIdx.x >> 2;
  int e = chunk * 256 + threadIdx.x;
  if (e >= E) return;
  int d = ei[E + e];
  int lo = p * PSIZE;
  if (d < lo || d >= lo + PSIZE) return;
  int pos = atomicAdd(&cursor[(attr[e] - 1) * NODES + d], 1);
  csr_src[pos] = ei[e];
}

// ---------------------------------------------------------------------------
// Gather (R12 body, identity worklist — proven R17): group id IS the
// km1-major bucket id. nwork = N / 2N / 3N selects km1 prefixes.
__global__ __launch_bounds__(256, 6) void gather_kernel(
    const __hip_bfloat16* __restrict__ src,
    const int* __restrict__ rowptr, const int* __restrict__ csr,
    __hip_bfloat16* __restrict__ ag0, __hip_bfloat16* __restrict__ ag1,
    __hip_bfloat16* __restrict__ ag2, int nwork) {
  int group = (blockIdx.x * 256 + threadIdx.x) >> 4;
  int lane16 = threadIdx.x & 15;
  if (group >= nwork) return;
  int km1 = (group >= 2 * NODES) ? 2 : ((group >= NODES) ? 1 : 0);
  int d = group - km1 * NODES;
  __hip_bfloat16* ag = (km1 == 0) ? ag0 : ((km1 == 1) ? ag1 : ag2);
  int beg = rowptr[group], end = rowptr[group + 1];   // (end-beg)%4 == 0
  float a0 = 0.f, a1 = 0.f, a2 = 0.f, a3 = 0.f,
        a4 = 0.f, a5 = 0.f, a6 = 0.f, a7 = 0.f;
  for (int base = beg; base < end; base += 16) {
    int idxv = csr[base + lane16];            // slack-allocated
    int cnt = end - base; if (cnt > 16) cnt = 16;
    int q0 = __shfl(idxv, 0, 16);
    int q1 = __shfl(idxv, 1, 16);
    int q2 = __shfl(idxv, 2, 16);
    int q3 = __shfl(idxv, 3, 16);
    uint4 v0 = *(const uint4*)(src + (long)q0 * DIM + lane16 * 8);
    uint4 v1 = *(const uint4*)(src + (long)q1 * DIM + lane16 * 8);
    uint4 v2 = *(const uint4*)(src + (long)q2 * DIM + lane16 * 8);
    uint4 v3 = *(const uint4*)(src + (long)q3 * DIM + lane16 * 8);
    for (int j = 0; j < cnt; j += 4) {
      uint4 c0 = v0, c1 = v1, c2 = v2, c3 = v3;
      if (j + 4 < cnt) {                      // pipeline next 4 rows
        q0 = __shfl(idxv, j + 4, 16);
        q1 = __shfl(idxv, j + 5, 16);
        q2 = __shfl(idxv, j + 6, 16);
        q3 = __shfl(idxv, j + 7, 16);
        v0 = *(const uint4*)(src + (long)q0 * DIM + lane16 * 8);
        v1 = *(const uint4*)(src + (long)q1 * DIM + lane16 * 8);
        v2 = *(const uint4*)(src + (long)q2 * DIM + lane16 * 8);
        v3 = *(const uint4*)(src + (long)q3 * DIM + lane16 * 8);
      }
      a0 += __uint_as_float(c0.x << 16) + __uint_as_float(c1.x << 16)
          + __uint_as_float(c2.x << 16) + __uint_as_float(c3.x << 16);
      a1 += __uint_as_float(c0.x & 0xffff0000u) + __uint_as_float(c1.x & 0xffff0000u)
          + __uint_as_float(c2.x & 0xffff0000u) + __uint_as_float(c3.x & 0xffff0000u);
      a2 += __uint_as_float(c0.y << 16) + __uint_as_float(c1.y << 16)
          + __uint_as_float(c2.y << 16) + __uint_as_float(c3.y << 16);
      a3 += __uint_as_float(c0.y & 0xffff0000u) + __uint_as_float(c1.y & 0xffff0000u)
          + __uint_as_float(c2.y & 0xffff0000u) + __uint_as_float(c3.y & 0xffff0000u);
      a4 += __uint_as_float(c0.z << 16) + __uint_as_float(c1.z << 16)
          + __uint_as_float(c2.z << 16) + __uint_as_float(c3.z << 16);
      a5 += __uint_as_float(c0.z & 0xffff0000u) + __uint_as_float(c1.z & 0xffff0000u)
          + __uint_as_float(c2.z & 0xffff0000u) + __uint_as_float(c3.z & 0xffff0000u);
      a6 += __uint_as_float(c0.w << 16) + __uint_as_float(c1.w << 16)
          + __uint_as_float(c2.w << 16) + __uint_as_float(c3.w << 16);
      a7 += __uint_as_float(c0.w & 0xffff0000u) + __uint_as_float(c1.w & 0xffff0000u)
          + __uint_as_float(c2.w & 0xffff0000u) + __uint_as_float(c3.w & 0xffff0000u);
    }
  }
  union { __hip_bfloat16 h[8]; uint4 u; } pk;
  pk.h[0] = __float2bfloat16(a0); pk.h[1] = __float2bfloat16(a1);
  pk.h[2] = __float2bfloat16(a2); pk.h[3] = __float2bfloat16(a3);
  pk.h[4] = __float2bfloat16(a4); pk.h[5] = __float2bfloat16(a5);
  pk.h[6] = __float2bfloat16(a6); pk.h[7] = __float2bfloat16(a7);
  *(uint4*)(ag + (long)d * DIM + lane16 * 8) = pk.u;
}

// ---------------------------------------------------------------------------
// Layer GEMM (R12 version, proven): bf16 node state, A-frags direct from
// global, B staged in LDS.
__global__ __launch_bounds__(256, 4) void lgemm_kernel(
    const __hip_bfloat16* __restrict__ xbSelf,
    const __hip_bfloat16* __restrict__ ag0,
    const __hip_bfloat16* __restrict__ ag1,
    const __hip_bfloat16* __restrict__ ag2,
    const __hip_bfloat16* __restrict__ WT,
    const float* __restrict__ bs_t,
    const float* __restrict__ bk_t,
    const float* __restrict__ epsp,
    __hip_bfloat16* __restrict__ xnb,   // bf16 out (layers 0/1)
    float* __restrict__ xn,             // f32 out (final layer) or null
    int t) {
  __shared__ __hip_bfloat16 b_lds[128 * LDS_STRIDE];  // 34816 B

  int tid = threadIdx.x;
  long row0 = (long)blockIdx.x * 64;
  int wave = tid >> 6, lane = tid & 63;
  int l15 = lane & 15, q = lane >> 4;
  long arow = row0 + wave * 16 + l15;

  const __hip_bfloat16* Asrc[4] = {xbSelf, ag0, ag1, ag2};
  f32x4 out[8];

  for (int p = 0; p <= t + 1; ++p) {
    if (p > 0) __syncthreads();
    const __hip_bfloat16* Am = Asrc[p];
    uint4 af[4];
#pragma unroll
    for (int k0i = 0; k0i < 4; ++k0i)
      af[k0i] = *(const uint4*)(Am + arow * DIM + k0i * 32 + 8 * q);
    const __hip_bfloat16* W = (p == 0) ? (WT + (long)t * 16384)
                                       : (WT + (long)(3 + t * 3 + (p - 1)) * 16384);
    {
      const uint4* bq = (const uint4*)W;
#pragma unroll
      for (int i = 0; i < 8; ++i) {
        int idx = tid + 256 * i;
        int n = idx >> 4, k8 = idx & 15;
        uint4 v = bq[idx];
        *(uint4*)(b_lds + n * LDS_STRIDE + k8 * 8) = v;
      }
    }
    __syncthreads();

    f32x4 acc[8] = {};
#pragma unroll
    for (int k0i = 0; k0i < 4; ++k0i) {
      bf16x8 a = __builtin_bit_cast(bf16x8, af[k0i]);
#pragma unroll
      for (int j = 0; j < 8; ++j) {
        bf16x8 bfr = *(const bf16x8*)(b_lds + (16 * j + l15) * LDS_STRIDE + k0i * 32 + 8 * q);
        acc[j] = __builtin_amdgcn_mfma_f32_16x16x32_bf16(a, bfr, acc[j], 0, 0, 0);
      }
    }
    if (p == 0) {
      float sc = 1.0f + *epsp;
#pragma unroll
      for (int j = 0; j < 8; ++j) {
        float b = bs_t[16 * j + l15];
#pragma unroll
        for (int r = 0; r < 4; ++r) out[j][r] = sc * fmaxf(acc[j][r] + b, 0.f);
      }
    } else {
      const float* bb = bk_t + (p - 1) * 128;
#pragma unroll
      for (int j = 0; j < 8; ++j) {
        float b = bb[16 * j + l15];
#pragma unroll
        for (int r = 0; r < 4; ++r) out[j][r] += fmaxf(acc[j][r] + b, 0.f);
      }
    }
  }

  long rbase = row0 + wave * 16 + q * 4;
  bool fin = (xn != nullptr);
#pragma unroll
  for (int j = 0; j < 8; ++j) {
    int col = 16 * j + l15;
#pragma unroll
    for (int r = 0; r < 4; ++r) {
      long grow = rbase + r;
      if (grow < NODES) {
        float res = __bfloat162float(xbSelf[grow * DIM + col]);
        float v = res + fmaxf(out[j][r], 0.f);
        if (fin) xn[grow * DIM + col] = v;
        else     xnb[grow * DIM + col] = __float2bfloat16(v);
      }
    }
  }
}

// ---------------------------------------------------------------------------
extern "C" void kernel_launch(void* const* d_in, const int* in_sizes, int n_in,
                              void* d_out, int out_size, void* d_ws, size_t ws_size,
                              hipStream_t stream) {
  const float* x    = (const float*)d_in[0];
  const int*   ei   = (const int*)d_in[1];
  const int*   attr = (const int*)d_in[2];
  const float* Ws   = (const float*)d_in[3];
  const float* bs   = (const float*)d_in[4];
  const float* Wk   = (const float*)d_in[5];
  const float* bk   = (const float*)d_in[6];
  const float* eps  = (const float*)d_in[7];
  float* out = (float*)d_out;

  char* ws = (char*)d_ws;
  size_t off = 0;
  auto alloc = [&](size_t bytes) { char* p = ws + off; off += (bytes + 255) & ~(size_t)255; return p; };
  const size_t ROWB = (size_t)NROWP * DIM * 2;
  __hip_bfloat16* xb0  = (__hip_bfloat16*)alloc(ROWB);
  __hip_bfloat16* xb1  = (__hip_bfloat16*)alloc(ROWB);
  __hip_bfloat16* xb2  = (__hip_bfloat16*)alloc(ROWB);
  __hip_bfloat16* agA0 = (__hip_bfloat16*)alloc(ROWB);  // src xb0: layer0 k=1
  __hip_bfloat16* agA1 = (__hip_bfloat16*)alloc(ROWB);  // src xb0: layer1 k=2
  __hip_bfloat16* agA2 = (__hip_bfloat16*)alloc(ROWB);  // src xb0: layer2 k=3
  __hip_bfloat16* agB0 = (__hip_bfloat16*)alloc(ROWB);  // src xb1: layer1 k=1
  __hip_bfloat16* agB1 = (__hip_bfloat16*)alloc(ROWB);  // src xb1: layer2 k=2
  __hip_bfloat16* agC0 = (__hip_bfloat16*)alloc(ROWB);  // src xb2: layer2 k=1
  __hip_bfloat16* WT   = (__hip_bfloat16*)alloc(12 * 16384 * 2);
  int* cursor    = (int*)alloc((size_t)NB3 * 4);
  int* rowptr    = (int*)alloc((size_t)(NB3 + 1) * 4 + 256);
  int* blocksums = (int*)alloc(1024 * 4);
  int* csr_src   = (int*)alloc((size_t)(EDGES + 4 * NB3 + 64) * 4);

  int egrid  = (EDGES + 255) / 256;        // 3125
  int igrid  = (int)(ND / 4 / 256);        // 6250

  hipLaunchKernelGGL(init_kernel, dim3(igrid), dim3(256), 0, stream,
                     x, Ws, Wk, xb0, xb1, xb2, WT, cursor);
  hipLaunchKernelGGL(hist_kernel, dim3(egrid), dim3(256), 0, stream, ei, attr, cursor, EDGES);
  hipLaunchKernelGGL(scan_a_kernel, dim3(NBLKS), dim3(256), 0, stream, cursor, rowptr, blocksums, NB3);
  hipLaunchKernelGGL(scanc_kernel, dim3(NBLKS), dim3(256), 0, stream,
                     rowptr, cursor, blocksums, csr_src, NB3);
  hipLaunchKernelGGL(fill_kernel, dim3(egrid * NPART), dim3(256), 0, stream, ei, attr, cursor, csr_src, EDGES);

  auto glaunch = [&](int nwork, const __hip_bfloat16* src, __hip_bfloat16* a0,
                     __hip_bfloat16* a1, __hip_bfloat16* a2) {
    int blocks = (nwork * 16 + 255) / 256;
    hipLaunchKernelGGL(gather_kernel, dim3(blocks), dim3(256), 0, stream,
                       src, rowptr, csr_src, a0, a1, a2, nwork);
  };
  int ggrid = (NODES + 63) / 64;   // 782

  // Gather A: all km1 from xb0.
  glaunch(3 * NODES, xb0, agA0, agA1, agA2);
  // Layer 0.
  hipLaunchKernelGGL(lgemm_kernel, dim3(ggrid), dim3(256), 0, stream,
                     xb0, agA0, agA0, agA0, WT, bs + 0, bk + 0, eps + 0,
                     xb1, (float*)nullptr, 0);
  // Gather B: km1 in {0,1} from xb1.
  glaunch(2 * NODES, xb1, agB0, agB1, agB1);
  // Layer 1: k=1 -> agB0 (xb1), k=2 -> agA1 (xb0).
  hipLaunchKernelGGL(lgemm_kernel, dim3(ggrid), dim3(256), 0, stream,
                     xb1, agB0, agA1, agA1, WT, bs + 128, bk + 3 * 128, eps + 1,
                     xb2, (float*)nullptr, 1);
  // Gather C: km1=0 from xb2.
  glaunch(NODES, xb2, agC0, agC0, agC0);
  // Layer 2: k=1 -> agC0 (xb2), k=2 -> agB1 (xb1), k=3 -> agA2 (xb0).
  hipLaunchKernelGGL(lgemm_kernel, dim3(ggrid), dim3(256), 0, stream,
                     xb2, agC0, agB1, agA2, WT, bs + 256, bk + 6 * 128, eps + 2,
                     (__hip_bfloat16*)nullptr, out, 2);
}